// Round 3
// baseline (332.041 us; speedup 1.0000x reference)
//
#include <hip/hip_runtime.h>

#define N_NODES 50000
#define IN_CH 128
#define HID 128
#define OUT_CH 40
#define N_LAYERS 3
#define N_EDGES 600000
#define HEADSTRIDE 16  // 64B per head slot (atomicExch line isolation)

typedef __attribute__((ext_vector_type(8))) short short8;
typedef __attribute__((ext_vector_type(4))) float floatx4;

static __device__ __forceinline__ unsigned short f32_to_bf16(float f) {
  unsigned u = __float_as_uint(f);
  unsigned r = 0x7FFFu + ((u >> 16) & 1u);  // RNE
  return (unsigned short)((u + r) >> 16);
}
static __device__ __forceinline__ float bf16_to_f32(unsigned short h) {
  return __uint_as_float(((unsigned)h) << 16);
}

#define CONV_BLOCKS 6250  // (N*128/4)/256
#define W_BLOCKS 408      // (6*16384 + 48*128)/256
#define HEAD_BLOCKS 782   // ceil(50000*16/4/256)

// == fused prep: x->bf16, W->WT bf16 [n][k], head=-1, phantom rows ==========
__global__ __launch_bounds__(256) void prep_all_kernel(
    const float* __restrict__ x, const float* __restrict__ W1,
    const float* __restrict__ W2, const float* __restrict__ Wc,
    unsigned short* __restrict__ xb, unsigned short* __restrict__ WT,
    unsigned short* __restrict__ WcT, unsigned short* __restrict__ hb1,
    int* __restrict__ head) {
  const int b = blockIdx.x;
  const int t = threadIdx.x;
  if (b < CONV_BLOCKS) {
    int i = (b * 256 + t) * 4;
    if (i < N_NODES * 128) {
      float4 v = *(const float4*)(x + i);
      ushort4 o;
      o.x = f32_to_bf16(v.x); o.y = f32_to_bf16(v.y);
      o.z = f32_to_bf16(v.z); o.w = f32_to_bf16(v.w);
      *(ushort4*)(xb + i) = o;
    }
  } else if (b < CONV_BLOCKS + W_BLOCKS) {
    int o = (b - CONV_BLOCKS) * 256 + t;
    if (o < 6 * 16384) {
      int mat = o >> 14;
      int r = o & 16383;
      int n = r >> 7;
      int k = r & 127;
      const float* W = (mat < 3) ? (W1 + (size_t)mat * 16384)
                                 : (W2 + (size_t)(mat - 3) * 16384);
      WT[(size_t)mat * 16384 + (size_t)n * 128 + k] =
          f32_to_bf16(W[(size_t)k * 128 + n]);
    } else if (o < 6 * 16384 + 48 * 128) {
      int r = o - 6 * 16384;
      int n = r >> 7;
      int k = r & 127;
      float v = (n < OUT_CH) ? Wc[(size_t)k * OUT_CH + n] : 0.0f;
      WcT[(size_t)n * 128 + k] = f32_to_bf16(v);
    }
  } else if (b < CONV_BLOCKS + W_BLOCKS + HEAD_BLOCKS) {
    int i = ((b - CONV_BLOCKS - W_BLOCKS) * 256 + t) * 4;
    if (i < N_NODES * HEADSTRIDE)
      *(int4*)(head + i) = make_int4(-1, -1, -1, -1);
  } else {
    // zero phantom rows (index N_NODES) of the two gather sources
    if (t < 128) xb[(size_t)N_NODES * 128 + t] = 0;
    else hb1[(size_t)N_NODES * 128 + (t - 128)] = 0;
  }
}

// ====== Linked-list CSR: 1 atomic/edge, payload store is COALESCED =========
// lst[e] = (src, next). Each thread's 4 edges are contiguous -> two int4
// stores (32B streamed). Total scattered transactions: 600k (atomicExch),
// half of the old atomicAdd+scattered-col scheme; scattered write-allocate
// traffic (35MB partial-line writebacks) eliminated.
#define CSR_BLOCKS 586  // ceil((600000/4)/256)
__global__ __launch_bounds__(256) void csr_kernel(
    const int* __restrict__ ei, int* __restrict__ head, int* __restrict__ lst) {
  int base = (blockIdx.x * 256 + threadIdx.x) * 4;
  if (base >= N_EDGES) return;
  int4 s4 = *(const int4*)(ei + base);
  int4 d4 = *(const int4*)(ei + N_EDGES + base);
  int n0 = atomicExch(&head[(size_t)d4.x * HEADSTRIDE], base + 0);
  int n1 = atomicExch(&head[(size_t)d4.y * HEADSTRIDE], base + 1);
  int n2 = atomicExch(&head[(size_t)d4.z * HEADSTRIDE], base + 2);
  int n3 = atomicExch(&head[(size_t)d4.w * HEADSTRIDE], base + 3);
  *(int4*)(lst + 2 * (size_t)base) = make_int4(s4.x, n0, s4.y, n1);
  *(int4*)(lst + 2 * (size_t)base + 4) = make_int4(s4.z, n2, s4.w, n3);
}

// ================= Aggregation (bf16): z = h[n] + sum_nbrs ==================
// One 64-lane wave walks TWO nodes' chains interleaved (2 independent
// dependent-load chases hide each other; 8 waves/SIMD hide the rest).
// Lane owns 2 channels (ushort2; 64 lanes = one 256B row per gather).
// Chain hop: 8B (src,next) load at wave-uniform addr -> readfirstlane ->
// gather row. Exhausted chains gather the phantom zero row (L1-hot).
__global__ __launch_bounds__(256) void aggregate_kernel(
    const unsigned short* __restrict__ h, const int* __restrict__ head,
    const int* __restrict__ lst, unsigned short* __restrict__ z) {
  const int w = threadIdx.x >> 6;
  int n0 = __builtin_amdgcn_readfirstlane(blockIdx.x * 8 + w * 2);
  int n1 = n0 + 1;
  const int q = threadIdx.x & 63;
  const size_t co = (size_t)q * 2;
  ushort2 sv0 = *(const ushort2*)(h + (size_t)n0 * 128 + co);
  ushort2 sv1 = *(const ushort2*)(h + (size_t)n1 * 128 + co);
  float a0x = bf16_to_f32(sv0.x), a0y = bf16_to_f32(sv0.y);
  float a1x = bf16_to_f32(sv1.x), a1y = bf16_to_f32(sv1.y);
  int e0 = __builtin_amdgcn_readfirstlane(head[(size_t)n0 * HEADSTRIDE]);
  int e1 = __builtin_amdgcn_readfirstlane(head[(size_t)n1 * HEADSTRIDE]);
  while (e0 != -1 || e1 != -1) {
    int s0 = N_NODES, nx0 = -1, s1 = N_NODES, nx1 = -1;
    if (e0 != -1) {
      int2 p = *(const int2*)(lst + 2 * (size_t)e0);
      s0 = p.x; nx0 = p.y;
    }
    if (e1 != -1) {
      int2 p = *(const int2*)(lst + 2 * (size_t)e1);
      s1 = p.x; nx1 = p.y;
    }
    s0 = __builtin_amdgcn_readfirstlane(s0);
    s1 = __builtin_amdgcn_readfirstlane(s1);
    ushort2 v0 = *(const ushort2*)(h + (size_t)s0 * 128 + co);
    ushort2 v1 = *(const ushort2*)(h + (size_t)s1 * 128 + co);
    a0x += bf16_to_f32(v0.x); a0y += bf16_to_f32(v0.y);
    a1x += bf16_to_f32(v1.x); a1y += bf16_to_f32(v1.y);
    e0 = __builtin_amdgcn_readfirstlane(nx0);
    e1 = __builtin_amdgcn_readfirstlane(nx1);
  }
  ushort2 o0, o1;
  o0.x = f32_to_bf16(a0x); o0.y = f32_to_bf16(a0y);
  o1.x = f32_to_bf16(a1x); o1.y = f32_to_bf16(a1y);
  *(ushort2*)(z + (size_t)n0 * 128 + co) = o0;
  *(ushort2*)(z + (size_t)n1 * 128 + co) = o1;
}

// ============ Fused layer MLP: Z = relu(relu(A@W1+b1)@W2+b2) ===============
// LDS-staged weights + 16 rows/wave. 64 rows/block, 4 waves (grid 782 =
// 3128 waves = 3 waves/SIMD). W staged into LDS once per GEMM (32KB, L2-hot
// source); B-frags become ds_read_b128. LDS = 34.8K (Wl) + 17.4K (T) = 52.2K
// -> 3 blocks/CU. Intermediate T rows wave-private; barriers only around Wl
// restage. LAST=true fuses the classifier (WcT direct-global; out f32).
// Frag layouts (measured m89/m91): A/B [idx=lane&15][k=(lane>>4)*8+j];
// C/D row=(lane>>4)*4+reg, col=lane&15.
template <bool LAST>
__global__ __launch_bounds__(256) void layer_pair_kernel(
    const unsigned short* __restrict__ A, const unsigned short* __restrict__ WT1,
    const float* __restrict__ b1, const unsigned short* __restrict__ WT2,
    const float* __restrict__ b2, unsigned short* __restrict__ Z,
    const unsigned short* __restrict__ WcT, const float* __restrict__ bc,
    float* __restrict__ out, int M) {
  __shared__ __align__(16) unsigned short Wl[128][136];  // staged weight
  __shared__ __align__(16) unsigned short T[64][136];    // activations
  const int tid = threadIdx.x;
  const int w = tid >> 6;
  const int lane = tid & 63;
  const int qg = lane >> 4;
  const int ln = lane & 15;
  const int row0 = blockIdx.x * 64;
  const int rbase = w * 16;
  const int r0 = row0 + rbase + ln;
  const short8 zero8 = {0, 0, 0, 0, 0, 0, 0, 0};

  // ---- stage WT1 -> Wl (2048 chunks of 8 bf16 over 256 threads) ----
#pragma unroll
  for (int j = 0; j < 8; ++j) {
    int slot = tid + j * 256;
    int row = slot >> 4;
    int kb = slot & 15;
    *(short8*)&Wl[row][kb * 8] = *(const short8*)(WT1 + (size_t)row * 128 + kb * 8);
  }
  __syncthreads();

  // ---- GEMM1: A direct-global, B from LDS ----
  floatx4 acc[8];
#pragma unroll
  for (int ct = 0; ct < 8; ++ct) acc[ct] = (floatx4){0.f, 0.f, 0.f, 0.f};
#pragma unroll
  for (int ks = 0; ks < 4; ++ks) {
    const int koff = ks * 32 + qg * 8;
    short8 a = (r0 < M) ? *(const short8*)(A + (size_t)r0 * 128 + koff) : zero8;
#pragma unroll
    for (int ct = 0; ct < 8; ++ct) {
      short8 b = *(const short8*)&Wl[ct * 16 + ln][koff];
      acc[ct] = __builtin_amdgcn_mfma_f32_16x16x32_bf16(a, b, acc[ct], 0, 0, 0);
    }
  }
  // ---- epilogue1 -> wave-private T rows (bias+relu+bf16) ----
#pragma unroll
  for (int ct = 0; ct < 8; ++ct) {
    float bv = b1[ct * 16 + ln];
#pragma unroll
    for (int r = 0; r < 4; ++r) {
      float v = fmaxf(acc[ct][r] + bv, 0.0f);
      T[rbase + qg * 4 + r][ct * 16 + ln] = f32_to_bf16(v);
    }
  }

  // ---- restage Wl with WT2 (all waves must be done with WT1) ----
  __syncthreads();
#pragma unroll
  for (int j = 0; j < 8; ++j) {
    int slot = tid + j * 256;
    int row = slot >> 4;
    int kb = slot & 15;
    *(short8*)&Wl[row][kb * 8] = *(const short8*)(WT2 + (size_t)row * 128 + kb * 8);
  }
  __syncthreads();

  // ---- GEMM2: A from own T rows, B from LDS ----
  floatx4 acc2[8];
#pragma unroll
  for (int ct = 0; ct < 8; ++ct) acc2[ct] = (floatx4){0.f, 0.f, 0.f, 0.f};
#pragma unroll
  for (int ks = 0; ks < 4; ++ks) {
    const int koff = ks * 32 + qg * 8;
    short8 a = *(const short8*)&T[rbase + ln][koff];
#pragma unroll
    for (int ct = 0; ct < 8; ++ct) {
      short8 b = *(const short8*)&Wl[ct * 16 + ln][koff];
      acc2[ct] = __builtin_amdgcn_mfma_f32_16x16x32_bf16(a, b, acc2[ct], 0, 0, 0);
    }
  }
  // ---- epilogue2 -> own T rows ----
#pragma unroll
  for (int ct = 0; ct < 8; ++ct) {
    float bv = b2[ct * 16 + ln];
#pragma unroll
    for (int r = 0; r < 4; ++r) {
      float v = fmaxf(acc2[ct][r] + bv, 0.0f);
      T[rbase + qg * 4 + r][ct * 16 + ln] = f32_to_bf16(v);
    }
  }

  if (LAST) {
    // ---- GEMM3 (classifier): A from own T rows, B = WcT direct-global ----
    floatx4 acc3[3];
#pragma unroll
    for (int ct = 0; ct < 3; ++ct) acc3[ct] = (floatx4){0.f, 0.f, 0.f, 0.f};
#pragma unroll
    for (int ks = 0; ks < 4; ++ks) {
      const int koff = ks * 32 + qg * 8;
      short8 a = *(const short8*)&T[rbase + ln][koff];
#pragma unroll
      for (int ct = 0; ct < 3; ++ct) {
        short8 b = *(const short8*)(WcT + (size_t)(ct * 16 + ln) * 128 + koff);
        acc3[ct] = __builtin_amdgcn_mfma_f32_16x16x32_bf16(a, b, acc3[ct], 0, 0, 0);
      }
    }
#pragma unroll
    for (int ct = 0; ct < 3; ++ct) {
      int colg = ct * 16 + ln;
      if (colg < OUT_CH) {
        float bv = bc[colg];
#pragma unroll
        for (int r = 0; r < 4; ++r) {
          int row = row0 + rbase + qg * 4 + r;
          if (row < M) out[(size_t)row * OUT_CH + colg] = acc3[ct][r] + bv;
        }
      }
    }
  } else {
    __syncthreads();
    // ---- cooperative coalesced store: 64 rows x 256B ----
#pragma unroll
    for (int j = 0; j < 4; ++j) {
      int slot = tid + j * 256;  // 0..1023 chunks of 8 bf16
      int row = slot >> 4;
      int kb = slot & 15;
      if (row0 + row < M) {
        short8 v = *(const short8*)&T[row][kb * 8];
        *(short8*)(Z + (size_t)(row0 + row) * 128 + kb * 8) = v;
      }
    }
  }
}

// ---------------------------------------------------------------------------
extern "C" void kernel_launch(void* const* d_in, const int* in_sizes, int n_in,
                              void* d_out, int out_size, void* d_ws,
                              size_t ws_size, hipStream_t stream) {
  const float* x = (const float*)d_in[0];
  const int* ei = (const int*)d_in[2];  // int32 [2, E]
  const float* W1 = (const float*)d_in[3];
  const float* b1 = (const float*)d_in[4];
  const float* W2 = (const float*)d_in[5];
  const float* b2 = (const float*)d_in[6];
  const float* Wc = (const float*)d_in[7];
  const float* bc = (const float*)d_in[8];
  float* out = (float*)d_out;

  // Node buffers have N+1 rows: row N_NODES is the phantom zero row.
  const size_t NF = (size_t)(N_NODES + 1) * 128;
  unsigned short* hb0 = (unsigned short*)d_ws;
  unsigned short* hb1 = hb0 + NF;
  unsigned short* xbf = hb1 + NF;
  unsigned short* WT = xbf + NF;         // 6*16384 bf16
  unsigned short* WcT = WT + 6 * 16384;  // 48*128 bf16
  int* head = (int*)(WcT + 48 * 128);    // [N * HEADSTRIDE], init -1
  int* lst = head + (size_t)N_NODES * HEADSTRIDE;  // [E * 2] (src, next)

  const dim3 blk(256);
  const int aggr_grid = N_NODES / 8;          // 6250 (2 nodes/wave)
  const int pair_grid = (N_NODES + 63) / 64;  // 782

  // ---- prep (conv_x + W transpose + head=-1 + phantom rows) ----
  prep_all_kernel<<<CONV_BLOCKS + W_BLOCKS + HEAD_BLOCKS + 1, blk, 0, stream>>>(
      x, W1, W2, Wc, xbf, WT, WcT, hb1, head);

  // ---- linked-list CSR: one atomicExch per edge, coalesced payload ----
  csr_kernel<<<CSR_BLOCKS, blk, 0, stream>>>(ei, head, lst);

  // ---- 3 GIN layers; classifier fused into the last pair ----
  // Fixed buffers: agg h->hb0; pair hb0->hb1; next h = hb1 (old h dead).
  const unsigned short* h = xbf;
  for (int l = 0; l < N_LAYERS; ++l) {
    aggregate_kernel<<<aggr_grid, blk, 0, stream>>>(h, head, lst, hb0);
    if (l < N_LAYERS - 1) {
      layer_pair_kernel<false><<<pair_grid, blk, 0, stream>>>(
          hb0, WT + (size_t)l * 16384, b1 + (size_t)l * 128,
          WT + (size_t)(3 + l) * 16384, b2 + (size_t)l * 128, hb1,
          nullptr, nullptr, nullptr, N_NODES);
      h = hb1;
    } else {
      layer_pair_kernel<true><<<pair_grid, blk, 0, stream>>>(
          hb0, WT + (size_t)l * 16384, b1 + (size_t)l * 128,
          WT + (size_t)(3 + l) * 16384, b2 + (size_t)l * 128, nullptr,
          WcT, bc, out, N_NODES);
    }
  }
}

// Round 4
// 313.229 us; speedup vs baseline: 1.0601x; 1.0601x over previous
//
#include <hip/hip_runtime.h>

#define N_NODES 50000
#define IN_CH 128
#define HID 128
#define OUT_CH 40
#define N_LAYERS 3
#define N_EDGES 600000
#define DSTRIDE 64    // fixed col slots/node; P(Poisson(12) > 64) ~ 1e-30
#define DEGSTRIDE 32  // 128B per counter

typedef __attribute__((ext_vector_type(8))) short short8;
typedef __attribute__((ext_vector_type(4))) float floatx4;

static __device__ __forceinline__ unsigned short f32_to_bf16(float f) {
  unsigned u = __float_as_uint(f);
  unsigned r = 0x7FFFu + ((u >> 16) & 1u);  // RNE
  return (unsigned short)((u + r) >> 16);
}
static __device__ __forceinline__ float bf16_to_f32(unsigned short h) {
  return __uint_as_float(((unsigned)h) << 16);
}

#define CONV_BLOCKS 6250  // (N*128/4)/256
#define W_BLOCKS 408      // (6*16384 + 48*128)/256
#define DEG_BLOCKS 1563   // ceil(50000*32/4/256)

// == fused prep: x->bf16, W->WT bf16 [n][k], deg=0, phantom rows ============
__global__ __launch_bounds__(256) void prep_all_kernel(
    const float* __restrict__ x, const float* __restrict__ W1,
    const float* __restrict__ W2, const float* __restrict__ Wc,
    unsigned short* __restrict__ xb, unsigned short* __restrict__ WT,
    unsigned short* __restrict__ WcT, unsigned short* __restrict__ hb0,
    unsigned short* __restrict__ hb1, int* __restrict__ deg) {
  const int b = blockIdx.x;
  const int t = threadIdx.x;
  if (b < CONV_BLOCKS) {
    int i = (b * 256 + t) * 4;
    if (i < N_NODES * 128) {
      float4 v = *(const float4*)(x + i);
      ushort4 o;
      o.x = f32_to_bf16(v.x); o.y = f32_to_bf16(v.y);
      o.z = f32_to_bf16(v.z); o.w = f32_to_bf16(v.w);
      *(ushort4*)(xb + i) = o;
    }
  } else if (b < CONV_BLOCKS + W_BLOCKS) {
    int o = (b - CONV_BLOCKS) * 256 + t;
    if (o < 6 * 16384) {
      int mat = o >> 14;
      int r = o & 16383;
      int n = r >> 7;
      int k = r & 127;
      const float* W = (mat < 3) ? (W1 + (size_t)mat * 16384)
                                 : (W2 + (size_t)(mat - 3) * 16384);
      WT[(size_t)mat * 16384 + (size_t)n * 128 + k] =
          f32_to_bf16(W[(size_t)k * 128 + n]);
    } else if (o < 6 * 16384 + 48 * 128) {
      int r = o - 6 * 16384;
      int n = r >> 7;
      int k = r & 127;
      float v = (n < OUT_CH) ? Wc[(size_t)k * OUT_CH + n] : 0.0f;
      WcT[(size_t)n * 128 + k] = f32_to_bf16(v);
    }
  } else if (b < CONV_BLOCKS + W_BLOCKS + DEG_BLOCKS) {
    int i = ((b - CONV_BLOCKS - W_BLOCKS) * 256 + t) * 4;
    if (i < N_NODES * DEGSTRIDE) *(int4*)(deg + i) = make_int4(0, 0, 0, 0);
  } else {
    // zero phantom rows (index N_NODES) of all three gather sources
    if (t < 128) {
      xb[(size_t)N_NODES * 128 + t] = 0;
      hb0[(size_t)N_NODES * 128 + t] = 0;
    } else {
      hb1[(size_t)N_NODES * 128 + (t - 128)] = 0;
    }
  }
}

// ========== CSR (fixed stride): one pass, padded deg counters ==============
__global__ __launch_bounds__(256) void csr_kernel(
    const int* __restrict__ ei, int* __restrict__ deg, int* __restrict__ col) {
  int e = blockIdx.x * 256 + threadIdx.x;
  if (e >= N_EDGES) return;
  int s = ei[e];
  int d = ei[N_EDGES + e];
  int pos = atomicAdd(&deg[(size_t)d * DEGSTRIDE], 1);
  col[(size_t)d * DSTRIDE + pos] = s;
}

// ===== Fused layer: T = aggregate(h) in LDS, then relu(relu(T@W1)@W2) ======
// Gather fused into the GEMM kernel: each wave aggregates its own 16 A-rows
// (R1 pattern: lane owns 2 channels, 16 row-gathers in flight per node,
// wave-uniform col ids via readfirstlane, tail clamped to phantom zero row)
// directly into the LDS T tile, then GEMM1 reads A from T like GEMM2 does.
// Removes the hb round-trip (25.6MB/layer) and 3 aggregate launches.
// Wl stage is issued BEFORE the gather so its latency hides under it.
// LDS = 34K (Wl) + 17K (T) = 52.2K -> 3 blocks/CU (12 waves/CU during
// gather; 16 outstanding 256B gathers per wave keeps the L3 path fed).
// Frag layouts (measured m89/m91): A/B [idx=lane&15][k=(lane>>4)*8+j];
// C/D row=(lane>>4)*4+reg, col=lane&15.
template <bool LAST>
__global__ __launch_bounds__(256) void fused_layer_kernel(
    const unsigned short* __restrict__ h, const int* __restrict__ deg,
    const int* __restrict__ col, const unsigned short* __restrict__ WT1,
    const float* __restrict__ b1, const unsigned short* __restrict__ WT2,
    const float* __restrict__ b2, unsigned short* __restrict__ Z,
    const unsigned short* __restrict__ WcT, const float* __restrict__ bc,
    float* __restrict__ out) {
  __shared__ __align__(16) unsigned short Wl[128][136];  // staged weight
  __shared__ __align__(16) unsigned short T[64][136];    // aggregated A rows
  const int tid = threadIdx.x;
  const int w = tid >> 6;
  const int lane = tid & 63;
  const int qg = lane >> 4;
  const int ln = lane & 15;
  const int row0 = blockIdx.x * 64;
  const int rbase = w * 16;

  // ---- stage WT1 -> Wl (issued first; completes under the gather) ----
#pragma unroll
  for (int j = 0; j < 8; ++j) {
    int slot = tid + j * 256;
    int row = slot >> 4;
    int kb = slot & 15;
    *(short8*)&Wl[row][kb * 8] = *(const short8*)(WT1 + (size_t)row * 128 + kb * 8);
  }

  // ---- gather phase: wave w aggregates its 16 rows into T ----
  const size_t co = (size_t)lane * 2;  // 2 channels per lane
  for (int idx = 0; idx < 16; ++idx) {
    int nid = row0 + rbase + idx;  // wave-uniform
    int hn = (nid < N_NODES) ? nid : N_NODES;
    ushort2 sv = *(const ushort2*)(h + (size_t)hn * 128 + co);
    float ax[8], ay[8];
#pragma unroll
    for (int k = 0; k < 8; ++k) { ax[k] = 0.f; ay[k] = 0.f; }
    ax[0] = bf16_to_f32(sv.x);
    ay[0] = bf16_to_f32(sv.y);
    int dg = 0;
    if (nid < N_NODES)
      dg = __builtin_amdgcn_readfirstlane(deg[(size_t)nid * DEGSTRIDE]);
    int cnt = (dg + 15) & ~15;
    const int* cp = col + (size_t)nid * DSTRIDE;
    for (int i = 0; i < cnt; i += 16) {
      int ss[16];
#pragma unroll
      for (int k = 0; k < 16; ++k) {
        int sl = cp[i + k];  // in-bounds; garbage beyond dg clamped below
        ss[k] = __builtin_amdgcn_readfirstlane((i + k < dg) ? sl : N_NODES);
      }
      ushort2 vv[16];
#pragma unroll
      for (int k = 0; k < 16; ++k)
        vv[k] = *(const ushort2*)(h + (size_t)ss[k] * 128 + co);
#pragma unroll
      for (int k = 0; k < 16; ++k) {
        ax[k & 7] += bf16_to_f32(vv[k].x);
        ay[k & 7] += bf16_to_f32(vv[k].y);
      }
    }
    float s0 = (ax[0] + ax[1]) + (ax[2] + ax[3]) + (ax[4] + ax[5]) + (ax[6] + ax[7]);
    float s1 = (ay[0] + ay[1]) + (ay[2] + ay[3]) + (ay[4] + ay[5]) + (ay[6] + ay[7]);
    ushort2 o;
    o.x = f32_to_bf16(s0);
    o.y = f32_to_bf16(s1);
    *(ushort2*)&T[rbase + idx][lane * 2] = o;
  }
  __syncthreads();  // Wl staged; T rows written (own rows suffice for GEMM1)

  // ---- GEMM1: A from own T rows, B from LDS ----
  floatx4 acc[8];
#pragma unroll
  for (int ct = 0; ct < 8; ++ct) acc[ct] = (floatx4){0.f, 0.f, 0.f, 0.f};
#pragma unroll
  for (int ks = 0; ks < 4; ++ks) {
    const int koff = ks * 32 + qg * 8;
    short8 a = *(const short8*)&T[rbase + ln][koff];
#pragma unroll
    for (int ct = 0; ct < 8; ++ct) {
      short8 b = *(const short8*)&Wl[ct * 16 + ln][koff];
      acc[ct] = __builtin_amdgcn_mfma_f32_16x16x32_bf16(a, b, acc[ct], 0, 0, 0);
    }
  }
  // ---- epilogue1 -> wave-private T rows (bias+relu+bf16) ----
#pragma unroll
  for (int ct = 0; ct < 8; ++ct) {
    float bv = b1[ct * 16 + ln];
#pragma unroll
    for (int r = 0; r < 4; ++r) {
      float v = fmaxf(acc[ct][r] + bv, 0.0f);
      T[rbase + qg * 4 + r][ct * 16 + ln] = f32_to_bf16(v);
    }
  }

  // ---- restage Wl with WT2 (all waves must be done with WT1) ----
  __syncthreads();
#pragma unroll
  for (int j = 0; j < 8; ++j) {
    int slot = tid + j * 256;
    int row = slot >> 4;
    int kb = slot & 15;
    *(short8*)&Wl[row][kb * 8] = *(const short8*)(WT2 + (size_t)row * 128 + kb * 8);
  }
  __syncthreads();

  // ---- GEMM2: A from own T rows, B from LDS ----
  floatx4 acc2[8];
#pragma unroll
  for (int ct = 0; ct < 8; ++ct) acc2[ct] = (floatx4){0.f, 0.f, 0.f, 0.f};
#pragma unroll
  for (int ks = 0; ks < 4; ++ks) {
    const int koff = ks * 32 + qg * 8;
    short8 a = *(const short8*)&T[rbase + ln][koff];
#pragma unroll
    for (int ct = 0; ct < 8; ++ct) {
      short8 b = *(const short8*)&Wl[ct * 16 + ln][koff];
      acc2[ct] = __builtin_amdgcn_mfma_f32_16x16x32_bf16(a, b, acc2[ct], 0, 0, 0);
    }
  }
  // ---- epilogue2 -> own T rows ----
#pragma unroll
  for (int ct = 0; ct < 8; ++ct) {
    float bv = b2[ct * 16 + ln];
#pragma unroll
    for (int r = 0; r < 4; ++r) {
      float v = fmaxf(acc2[ct][r] + bv, 0.0f);
      T[rbase + qg * 4 + r][ct * 16 + ln] = f32_to_bf16(v);
    }
  }

  if (LAST) {
    // ---- GEMM3 (classifier): A from own T rows, B = WcT direct-global ----
    floatx4 acc3[3];
#pragma unroll
    for (int ct = 0; ct < 3; ++ct) acc3[ct] = (floatx4){0.f, 0.f, 0.f, 0.f};
#pragma unroll
    for (int ks = 0; ks < 4; ++ks) {
      const int koff = ks * 32 + qg * 8;
      short8 a = *(const short8*)&T[rbase + ln][koff];
#pragma unroll
      for (int ct = 0; ct < 3; ++ct) {
        short8 b = *(const short8*)(WcT + (size_t)(ct * 16 + ln) * 128 + koff);
        acc3[ct] = __builtin_amdgcn_mfma_f32_16x16x32_bf16(a, b, acc3[ct], 0, 0, 0);
      }
    }
#pragma unroll
    for (int ct = 0; ct < 3; ++ct) {
      int colg = ct * 16 + ln;
      if (colg < OUT_CH) {
        float bv = bc[colg];
#pragma unroll
        for (int r = 0; r < 4; ++r) {
          int row = row0 + rbase + qg * 4 + r;
          if (row < N_NODES) out[(size_t)row * OUT_CH + colg] = acc3[ct][r] + bv;
        }
      }
    }
  } else {
    __syncthreads();
    // ---- cooperative coalesced store: 64 rows x 256B ----
#pragma unroll
    for (int j = 0; j < 4; ++j) {
      int slot = tid + j * 256;  // 0..1023 chunks of 8 bf16
      int row = slot >> 4;
      int kb = slot & 15;
      if (row0 + row < N_NODES) {
        short8 v = *(const short8*)&T[row][kb * 8];
        *(short8*)(Z + (size_t)(row0 + row) * 128 + kb * 8) = v;
      }
    }
  }
}

// ---------------------------------------------------------------------------
extern "C" void kernel_launch(void* const* d_in, const int* in_sizes, int n_in,
                              void* d_out, int out_size, void* d_ws,
                              size_t ws_size, hipStream_t stream) {
  const float* x = (const float*)d_in[0];
  const int* ei = (const int*)d_in[2];  // int32 [2, E]
  const float* W1 = (const float*)d_in[3];
  const float* b1 = (const float*)d_in[4];
  const float* W2 = (const float*)d_in[5];
  const float* b2 = (const float*)d_in[6];
  const float* Wc = (const float*)d_in[7];
  const float* bc = (const float*)d_in[8];
  float* out = (float*)d_out;

  // Node buffers have N+1 rows: row N_NODES is the phantom zero row.
  const size_t NF = (size_t)(N_NODES + 1) * 128;
  unsigned short* hb0 = (unsigned short*)d_ws;
  unsigned short* hb1 = hb0 + NF;
  unsigned short* xbf = hb1 + NF;
  unsigned short* WT = xbf + NF;         // 6*16384 bf16
  unsigned short* WcT = WT + 6 * 16384;  // 48*128 bf16
  int* deg = (int*)(WcT + 48 * 128);     // [N * DEGSTRIDE] (128B-padded ctrs)
  int* col = deg + (size_t)N_NODES * DEGSTRIDE;  // [N * DSTRIDE]

  const dim3 blk(256);
  const int edge_grid = (N_EDGES + 255) / 256;   // 2344
  const int layer_grid = (N_NODES + 63) / 64;    // 782

  // ---- prep (conv_x + W transpose + padded deg=0 + phantom rows) ----
  prep_all_kernel<<<CONV_BLOCKS + W_BLOCKS + DEG_BLOCKS + 1, blk, 0, stream>>>(
      x, W1, W2, Wc, xbf, WT, WcT, hb0, hb1, deg);

  // ---- CSR, one pass: deg count + fixed-stride slot fill ----
  csr_kernel<<<edge_grid, blk, 0, stream>>>(ei, deg, col);

  // ---- 3 fused GIN layers (gather+MLP); classifier fused into the last ----
  // Flow: xbf -> hb0 -> hb1 -> out. Phantom rows pre-zeroed in all three.
  fused_layer_kernel<false><<<layer_grid, blk, 0, stream>>>(
      xbf, deg, col, WT + 0 * 16384, b1 + 0 * 128, WT + 3 * 16384, b2 + 0 * 128,
      hb0, nullptr, nullptr, nullptr);
  fused_layer_kernel<false><<<layer_grid, blk, 0, stream>>>(
      hb0, deg, col, WT + 1 * 16384, b1 + 1 * 128, WT + 4 * 16384, b2 + 1 * 128,
      hb1, nullptr, nullptr, nullptr);
  fused_layer_kernel<true><<<layer_grid, blk, 0, stream>>>(
      hb1, deg, col, WT + 2 * 16384, b1 + 2 * 128, WT + 5 * 16384, b2 + 2 * 128,
      nullptr, WcT, bc, out);
}

// Round 5
// 243.202 us; speedup vs baseline: 1.3653x; 1.2879x over previous
//
#include <hip/hip_runtime.h>

#define N_NODES 50000
#define IN_CH 128
#define HID 128
#define OUT_CH 40
#define N_LAYERS 3
#define N_EDGES 600000
#define DSTRIDE 64    // fixed col slots/node; P(Poisson(12) > 64) ~ 1e-30
#define DEGSTRIDE 16  // 64B per counter

typedef __attribute__((ext_vector_type(8))) short short8;
typedef __attribute__((ext_vector_type(4))) float floatx4;

static __device__ __forceinline__ unsigned short f32_to_bf16(float f) {
  unsigned u = __float_as_uint(f);
  unsigned r = 0x7FFFu + ((u >> 16) & 1u);  // RNE
  return (unsigned short)((u + r) >> 16);
}
static __device__ __forceinline__ float bf16_to_f32(unsigned short h) {
  return __uint_as_float(((unsigned)h) << 16);
}

// ---- tiny deg-zero kernel (must complete before prep_csr's csr blocks) ----
#define ZERO_BLOCKS 782  // ceil(50000*16/4/256)
__global__ __launch_bounds__(256) void zero_deg_kernel(int* __restrict__ deg) {
  int i = (blockIdx.x * 256 + threadIdx.x) * 4;
  if (i < N_NODES * DEGSTRIDE) *(int4*)(deg + i) = make_int4(0, 0, 0, 0);
}

#define CSRB 586          // ceil((600000/4)/256) — csr blocks, FIRST in grid
#define CONV_BLOCKS 6250  // (N*128/4)/256
#define W_BLOCKS 408      // (6*16384 + 48*128)/256

// == combined prep + CSR: csr blocks overlap with streaming prep blocks =====
// csr is atomic-latency-bound (11% HBM, 0.4% VALU standalone); prep is pure
// streaming BW. One grid runs both concurrently: csr blocks dispatched first
// so their ~42us atomic wall hides under prep's 38MB of streaming traffic.
// Safe: csr only writes deg/col (zeroed by the prior tiny kernel; read by
// nobody here); prep blocks touch disjoint buffers.
__global__ __launch_bounds__(256) void prep_csr_kernel(
    const float* __restrict__ x, const float* __restrict__ W1,
    const float* __restrict__ W2, const float* __restrict__ Wc,
    const int* __restrict__ ei, unsigned short* __restrict__ xb,
    unsigned short* __restrict__ WT, unsigned short* __restrict__ WcT,
    unsigned short* __restrict__ hb1, int* __restrict__ deg,
    int* __restrict__ col) {
  const int b = blockIdx.x;
  const int t = threadIdx.x;
  if (b < CSRB) {
    // ---- CSR: 4 edges/thread (atomic ILP), fixed-stride slot fill ----
    int base = (b * 256 + t) * 4;
    if (base < N_EDGES) {
      int4 s4 = *(const int4*)(ei + base);
      int4 d4 = *(const int4*)(ei + N_EDGES + base);
      int p0 = atomicAdd(&deg[(size_t)d4.x * DEGSTRIDE], 1);
      int p1 = atomicAdd(&deg[(size_t)d4.y * DEGSTRIDE], 1);
      int p2 = atomicAdd(&deg[(size_t)d4.z * DEGSTRIDE], 1);
      int p3 = atomicAdd(&deg[(size_t)d4.w * DEGSTRIDE], 1);
      col[(size_t)d4.x * DSTRIDE + p0] = s4.x;
      col[(size_t)d4.y * DSTRIDE + p1] = s4.y;
      col[(size_t)d4.z * DSTRIDE + p2] = s4.z;
      col[(size_t)d4.w * DSTRIDE + p3] = s4.w;
    }
  } else if (b < CSRB + CONV_BLOCKS) {
    int i = ((b - CSRB) * 256 + t) * 4;
    if (i < N_NODES * 128) {
      float4 v = *(const float4*)(x + i);
      ushort4 o;
      o.x = f32_to_bf16(v.x); o.y = f32_to_bf16(v.y);
      o.z = f32_to_bf16(v.z); o.w = f32_to_bf16(v.w);
      *(ushort4*)(xb + i) = o;
    }
  } else if (b < CSRB + CONV_BLOCKS + W_BLOCKS) {
    int o = (b - CSRB - CONV_BLOCKS) * 256 + t;
    if (o < 6 * 16384) {
      int mat = o >> 14;
      int r = o & 16383;
      int n = r >> 7;
      int k = r & 127;
      const float* W = (mat < 3) ? (W1 + (size_t)mat * 16384)
                                 : (W2 + (size_t)(mat - 3) * 16384);
      WT[(size_t)mat * 16384 + (size_t)n * 128 + k] =
          f32_to_bf16(W[(size_t)k * 128 + n]);
    } else if (o < 6 * 16384 + 48 * 128) {
      int r = o - 6 * 16384;
      int n = r >> 7;
      int k = r & 127;
      float v = (n < OUT_CH) ? Wc[(size_t)k * OUT_CH + n] : 0.0f;
      WcT[(size_t)n * 128 + k] = f32_to_bf16(v);
    }
  } else {
    // zero phantom rows (index N_NODES) of the two gather sources
    if (t < 128) xb[(size_t)N_NODES * 128 + t] = 0;
    else hb1[(size_t)N_NODES * 128 + (t - 128)] = 0;
  }
}

// ================= Aggregation (bf16): z = h[n] + sum_nbrs ==================
// One 64-lane wave per node; lane owns 2 channels (ushort2; 64 lanes = one
// 256B row per gather). deg/col wave-uniform via readfirstlane -> scalar
// loads. Loop bound padded to 16; tail slots clamped (scalar cndmask) to the
// phantom zero row — col needs no prefill, garbage loads are discarded.
__global__ __launch_bounds__(256) void aggregate_kernel(
    const unsigned short* __restrict__ h, const int* __restrict__ deg,
    const int* __restrict__ col, unsigned short* __restrict__ z) {
  int n = __builtin_amdgcn_readfirstlane(blockIdx.x * 4 + (threadIdx.x >> 6));
  int q = threadIdx.x & 63;
  const size_t co = (size_t)q * 2;
  ushort2 sv = *(const ushort2*)(h + (size_t)n * 128 + co);
  float ax[8], ay[8];
#pragma unroll
  for (int k = 0; k < 8; ++k) { ax[k] = 0.f; ay[k] = 0.f; }
  ax[0] = bf16_to_f32(sv.x);
  ay[0] = bf16_to_f32(sv.y);
  int dg = __builtin_amdgcn_readfirstlane(deg[(size_t)n * DEGSTRIDE]);
  int cnt = (dg + 15) & ~15;
  const int* cp = col + (size_t)n * DSTRIDE;
  for (int i = 0; i < cnt; i += 16) {
    int ss[16];
#pragma unroll
    for (int k = 0; k < 16; ++k) {
      int sl = cp[i + k];  // in-bounds; garbage beyond dg is clamped below
      ss[k] = __builtin_amdgcn_readfirstlane((i + k < dg) ? sl : N_NODES);
    }
    ushort2 vv[16];
#pragma unroll
    for (int k = 0; k < 16; ++k)
      vv[k] = *(const ushort2*)(h + (size_t)ss[k] * 128 + co);
#pragma unroll
    for (int k = 0; k < 16; ++k) {
      ax[k & 7] += bf16_to_f32(vv[k].x);
      ay[k & 7] += bf16_to_f32(vv[k].y);
    }
  }
  float s0 = (ax[0] + ax[1]) + (ax[2] + ax[3]) + (ax[4] + ax[5]) + (ax[6] + ax[7]);
  float s1 = (ay[0] + ay[1]) + (ay[2] + ay[3]) + (ay[4] + ay[5]) + (ay[6] + ay[7]);
  ushort2 o;
  o.x = f32_to_bf16(s0);
  o.y = f32_to_bf16(s1);
  *(ushort2*)(z + (size_t)n * 128 + co) = o;
}

// ============ Fused layer MLP: Z = relu(relu(A@W1+b1)@W2+b2) ===============
// LDS-staged weights + 16 rows/wave. 64 rows/block, 4 waves (grid 782 =
// 3128 waves = 3 waves/SIMD). W staged into LDS once per GEMM (32KB, L2-hot
// source); B-frags become ds_read_b128. LDS = 34.8K (Wl) + 17.4K (T) = 52.2K
// -> 3 blocks/CU. Intermediate T rows wave-private; barriers only around Wl
// restage. LAST=true fuses the classifier (WcT direct-global; out f32).
// Frag layouts (measured m89/m91): A/B [idx=lane&15][k=(lane>>4)*8+j];
// C/D row=(lane>>4)*4+reg, col=lane&15.
template <bool LAST>
__global__ __launch_bounds__(256) void layer_pair_kernel(
    const unsigned short* __restrict__ A, const unsigned short* __restrict__ WT1,
    const float* __restrict__ b1, const unsigned short* __restrict__ WT2,
    const float* __restrict__ b2, unsigned short* __restrict__ Z,
    const unsigned short* __restrict__ WcT, const float* __restrict__ bc,
    float* __restrict__ out, int M) {
  __shared__ __align__(16) unsigned short Wl[128][136];  // staged weight
  __shared__ __align__(16) unsigned short T[64][136];    // activations
  const int tid = threadIdx.x;
  const int w = tid >> 6;
  const int lane = tid & 63;
  const int qg = lane >> 4;
  const int ln = lane & 15;
  const int row0 = blockIdx.x * 64;
  const int rbase = w * 16;
  const int r0 = row0 + rbase + ln;
  const short8 zero8 = {0, 0, 0, 0, 0, 0, 0, 0};

  // ---- stage WT1 -> Wl (2048 chunks of 8 bf16 over 256 threads) ----
#pragma unroll
  for (int j = 0; j < 8; ++j) {
    int slot = tid + j * 256;
    int row = slot >> 4;
    int kb = slot & 15;
    *(short8*)&Wl[row][kb * 8] = *(const short8*)(WT1 + (size_t)row * 128 + kb * 8);
  }
  __syncthreads();

  // ---- GEMM1: A direct-global, B from LDS ----
  floatx4 acc[8];
#pragma unroll
  for (int ct = 0; ct < 8; ++ct) acc[ct] = (floatx4){0.f, 0.f, 0.f, 0.f};
#pragma unroll
  for (int ks = 0; ks < 4; ++ks) {
    const int koff = ks * 32 + qg * 8;
    short8 a = (r0 < M) ? *(const short8*)(A + (size_t)r0 * 128 + koff) : zero8;
#pragma unroll
    for (int ct = 0; ct < 8; ++ct) {
      short8 b = *(const short8*)&Wl[ct * 16 + ln][koff];
      acc[ct] = __builtin_amdgcn_mfma_f32_16x16x32_bf16(a, b, acc[ct], 0, 0, 0);
    }
  }
  // ---- epilogue1 -> wave-private T rows (bias+relu+bf16) ----
#pragma unroll
  for (int ct = 0; ct < 8; ++ct) {
    float bv = b1[ct * 16 + ln];
#pragma unroll
    for (int r = 0; r < 4; ++r) {
      float v = fmaxf(acc[ct][r] + bv, 0.0f);
      T[rbase + qg * 4 + r][ct * 16 + ln] = f32_to_bf16(v);
    }
  }

  // ---- restage Wl with WT2 (all waves must be done with WT1) ----
  __syncthreads();
#pragma unroll
  for (int j = 0; j < 8; ++j) {
    int slot = tid + j * 256;
    int row = slot >> 4;
    int kb = slot & 15;
    *(short8*)&Wl[row][kb * 8] = *(const short8*)(WT2 + (size_t)row * 128 + kb * 8);
  }
  __syncthreads();

  // ---- GEMM2: A from own T rows, B from LDS ----
  floatx4 acc2[8];
#pragma unroll
  for (int ct = 0; ct < 8; ++ct) acc2[ct] = (floatx4){0.f, 0.f, 0.f, 0.f};
#pragma unroll
  for (int ks = 0; ks < 4; ++ks) {
    const int koff = ks * 32 + qg * 8;
    short8 a = *(const short8*)&T[rbase + ln][koff];
#pragma unroll
    for (int ct = 0; ct < 8; ++ct) {
      short8 b = *(const short8*)&Wl[ct * 16 + ln][koff];
      acc2[ct] = __builtin_amdgcn_mfma_f32_16x16x32_bf16(a, b, acc2[ct], 0, 0, 0);
    }
  }
  // ---- epilogue2 -> own T rows ----
#pragma unroll
  for (int ct = 0; ct < 8; ++ct) {
    float bv = b2[ct * 16 + ln];
#pragma unroll
    for (int r = 0; r < 4; ++r) {
      float v = fmaxf(acc2[ct][r] + bv, 0.0f);
      T[rbase + qg * 4 + r][ct * 16 + ln] = f32_to_bf16(v);
    }
  }

  if (LAST) {
    // ---- GEMM3 (classifier): A from own T rows, B = WcT direct-global ----
    floatx4 acc3[3];
#pragma unroll
    for (int ct = 0; ct < 3; ++ct) acc3[ct] = (floatx4){0.f, 0.f, 0.f, 0.f};
#pragma unroll
    for (int ks = 0; ks < 4; ++ks) {
      const int koff = ks * 32 + qg * 8;
      short8 a = *(const short8*)&T[rbase + ln][koff];
#pragma unroll
      for (int ct = 0; ct < 3; ++ct) {
        short8 b = *(const short8*)(WcT + (size_t)(ct * 16 + ln) * 128 + koff);
        acc3[ct] = __builtin_amdgcn_mfma_f32_16x16x32_bf16(a, b, acc3[ct], 0, 0, 0);
      }
    }
#pragma unroll
    for (int ct = 0; ct < 3; ++ct) {
      int colg = ct * 16 + ln;
      if (colg < OUT_CH) {
        float bv = bc[colg];
#pragma unroll
        for (int r = 0; r < 4; ++r) {
          int row = row0 + rbase + qg * 4 + r;
          if (row < M) out[(size_t)row * OUT_CH + colg] = acc3[ct][r] + bv;
        }
      }
    }
  } else {
    __syncthreads();
    // ---- cooperative coalesced store: 64 rows x 256B ----
#pragma unroll
    for (int j = 0; j < 4; ++j) {
      int slot = tid + j * 256;  // 0..1023 chunks of 8 bf16
      int row = slot >> 4;
      int kb = slot & 15;
      if (row0 + row < M) {
        short8 v = *(const short8*)&T[row][kb * 8];
        *(short8*)(Z + (size_t)(row0 + row) * 128 + kb * 8) = v;
      }
    }
  }
}

// ---------------------------------------------------------------------------
extern "C" void kernel_launch(void* const* d_in, const int* in_sizes, int n_in,
                              void* d_out, int out_size, void* d_ws,
                              size_t ws_size, hipStream_t stream) {
  const float* x = (const float*)d_in[0];
  const int* ei = (const int*)d_in[2];  // int32 [2, E]
  const float* W1 = (const float*)d_in[3];
  const float* b1 = (const float*)d_in[4];
  const float* W2 = (const float*)d_in[5];
  const float* b2 = (const float*)d_in[6];
  const float* Wc = (const float*)d_in[7];
  const float* bc = (const float*)d_in[8];
  float* out = (float*)d_out;

  // Node buffers have N+1 rows: row N_NODES is the phantom zero row.
  const size_t NF = (size_t)(N_NODES + 1) * 128;
  unsigned short* hb0 = (unsigned short*)d_ws;
  unsigned short* hb1 = hb0 + NF;
  unsigned short* xbf = hb1 + NF;
  unsigned short* WT = xbf + NF;         // 6*16384 bf16
  unsigned short* WcT = WT + 6 * 16384;  // 48*128 bf16
  int* deg = (int*)(WcT + 48 * 128);     // [N * DEGSTRIDE] (64B-padded ctrs)
  int* col = deg + (size_t)N_NODES * DEGSTRIDE;  // [N * DSTRIDE]

  const dim3 blk(256);
  const int aggr_grid = N_NODES / 4;          // 12500
  const int pair_grid = (N_NODES + 63) / 64;  // 782

  // ---- deg = 0 (tiny; must complete before prep_csr's csr blocks) ----
  zero_deg_kernel<<<ZERO_BLOCKS, blk, 0, stream>>>(deg);

  // ---- combined prep + CSR: csr atomic wall overlaps streaming prep ----
  prep_csr_kernel<<<CSRB + CONV_BLOCKS + W_BLOCKS + 1, blk, 0, stream>>>(
      x, W1, W2, Wc, ei, xbf, WT, WcT, hb1, deg, col);

  // ---- 3 GIN layers; classifier fused into the last pair ----
  // Fixed buffers: agg h->hb0; pair hb0->hb1; next h = hb1 (old h dead).
  const unsigned short* h = xbf;
  for (int l = 0; l < N_LAYERS; ++l) {
    aggregate_kernel<<<aggr_grid, blk, 0, stream>>>(h, deg, col, hb0);
    if (l < N_LAYERS - 1) {
      layer_pair_kernel<false><<<pair_grid, blk, 0, stream>>>(
          hb0, WT + (size_t)l * 16384, b1 + (size_t)l * 128,
          WT + (size_t)(3 + l) * 16384, b2 + (size_t)l * 128, hb1,
          nullptr, nullptr, nullptr, N_NODES);
      h = hb1;
    } else {
      layer_pair_kernel<true><<<pair_grid, blk, 0, stream>>>(
          hb0, WT + (size_t)l * 16384, b1 + (size_t)l * 128,
          WT + (size_t)(3 + l) * 16384, b2 + (size_t)l * 128, nullptr,
          WcT, bc, out, N_NODES);
    }
  }
}